// Round 3
// baseline (630.706 us; speedup 1.0000x reference)
//
#include <hip/hip_runtime.h>
#include <cstdint>
#include <cstddef>

typedef __bf16 bf16x8 __attribute__((ext_vector_type(8)));
typedef float f32x4 __attribute__((ext_vector_type(4)));
typedef unsigned short u16;
typedef u16 u16x4 __attribute__((ext_vector_type(4)));
typedef u16 u16x8 __attribute__((ext_vector_type(8)));

// fp32 -> bf16 round-to-nearest-even
__device__ __forceinline__ u16 f2bf(float f) {
  union { float f; unsigned u; } v; v.f = f;
  return (u16)((v.u + 0x7FFFu + ((v.u >> 16) & 1u)) >> 16);
}

// async global->LDS, 16B per lane; LDS dest = uniform base + lane*16
__device__ __forceinline__ void gl_lds16(const void* g, void* l) {
  __builtin_amdgcn_global_load_lds((__attribute__((address_space(1))) void*)(g),
                                   (__attribute__((address_space(3))) void*)(l), 16, 0, 0);
}

// ---------------------------------------------------------------------------
// Pre-pass: gather (route) + transpose + fp32->bf16.
// in: [*, K, N] fp32 plane selected by route[z] (or z if route==null)
// out: [z, N, K] bf16 (n-major)
// ---------------------------------------------------------------------------
__global__ void transpose_cvt(const float* __restrict__ in, const int* __restrict__ route,
                              u16* __restrict__ out, int K, int N) {
  __shared__ float t[32][33];
  const int a = blockIdx.z;
  const int src = route ? route[a] : a;
  const float* ip = in + (size_t)src * K * N;
  u16* op = out + (size_t)a * K * N;
  const int k0 = blockIdx.x * 32, n0 = blockIdx.y * 32;
  const int tx = threadIdx.x, ty = threadIdx.y;  // (32, 8)
#pragma unroll
  for (int i = 0; i < 4; ++i)
    t[ty + i * 8][tx] = ip[(size_t)(k0 + ty + i * 8) * N + n0 + tx];
  __syncthreads();
#pragma unroll
  for (int i = 0; i < 4; ++i)
    op[(size_t)(n0 + ty + i * 8) * K + k0 + tx] = f2bf(t[tx][ty + i * 8]);
}

// ---------------------------------------------------------------------------
// gemm1: x1 = relu(x0 @ Ws + bs).  BM=64, BN=512, BK=32.
// 256 thr / 4 waves, wave-tile 64x128 (waves split n).  2 blocks/CU.
// A fp32 register-load + inline cvt (prefetch distance = full compute phase);
// B via global_load_lds.  Output bf16 to (a, b, h) planes.
// ---------------------------------------------------------------------------
__global__ __launch_bounds__(256, 2)
void gemm1(const float* __restrict__ X0, const u16* __restrict__ Wst,
           const float* __restrict__ bsh, u16* __restrict__ X1) {
  __shared__ u16 As[2048];    // [64 m][32 k], XOR-granule swizzled
  __shared__ u16 Bs[16384];   // [512 n][32 k], XOR-granule swizzled
  const int tid = threadIdx.x;
  const int w = tid >> 6, l = tid & 63;
  const int r = l & 15, q = l >> 4;
  const int m0 = blockIdx.x * 64;

  // A staging: one u16x8 granule per thread per iter
  const int arow = tid >> 2, akq = tid & 3;
  const float* gA = X0 + (size_t)(m0 + arow) * 512 + akq * 8;
  const int adst = arow * 32 + ((akq ^ ((arow >> 1) & 3)) << 3);

  // B staging: 8 gl_lds16 slots per thread (512 rows x 32 k = 32 KB)
  int bsrc[8], bdst[8];
#pragma unroll
  for (int c = 0; c < 8; ++c) {
    const int p = c * 256 + tid;
    const int n = p >> 2, s = p & 3;
    bsrc[c] = n * 512 + ((s ^ ((n >> 1) & 3)) << 3);
    bdst[c] = p * 8;
  }

  // fragment offsets (conflict-free: consecutive-8-lane groups span 32 banks)
  int aoff[4], boff[8];
#pragma unroll
  for (int t = 0; t < 4; ++t)
    aoff[t] = (t * 16 + r) * 32 + ((q ^ ((r >> 1) & 3)) << 3);
#pragma unroll
  for (int t = 0; t < 8; ++t)
    boff[t] = (w * 128 + t * 16 + r) * 32 + ((q ^ ((r >> 1) & 3)) << 3);

  f32x4 acc[4][8];
#pragma unroll
  for (int mt = 0; mt < 4; ++mt)
#pragma unroll
    for (int nt = 0; nt < 8; ++nt) acc[mt][nt] = (f32x4){0.f, 0.f, 0.f, 0.f};

  float4 a0 = *(const float4*)gA;
  float4 a1 = *(const float4*)(gA + 4);

  for (int kt = 0; kt < 16; ++kt) {
    __syncthreads();                      // previous compute's LDS reads done
#pragma unroll
    for (int c = 0; c < 8; ++c) gl_lds16(Wst + bsrc[c] + kt * 32, &Bs[bdst[c]]);
    {
      const u16x8 d = { f2bf(a0.x), f2bf(a0.y), f2bf(a0.z), f2bf(a0.w),
                        f2bf(a1.x), f2bf(a1.y), f2bf(a1.z), f2bf(a1.w) };
      *(u16x8*)&As[adst] = d;
    }
    __syncthreads();                      // staging visible (vmcnt drained)
    if (kt < 15) {                        // prefetch next A (covered by compute)
      a0 = *(const float4*)(gA + (kt + 1) * 32);
      a1 = *(const float4*)(gA + (kt + 1) * 32 + 4);
    }
    bf16x8 af[4], bv[8];
#pragma unroll
    for (int t = 0; t < 4; ++t) af[t] = *(const bf16x8*)&As[aoff[t]];
#pragma unroll
    for (int t = 0; t < 8; ++t) bv[t] = *(const bf16x8*)&Bs[boff[t]];
#pragma unroll
    for (int mt = 0; mt < 4; ++mt)
#pragma unroll
      for (int nt = 0; nt < 8; ++nt)      // swapped operands: lane = C[m=r][n=q*4+j]
        acc[mt][nt] = __builtin_amdgcn_mfma_f32_16x16x32_bf16(bv[nt], af[mt], acc[mt][nt], 0, 0, 0);
  }

  // epilogue: relu+bias, write bf16 to agent-major planes [a][b][h]
#pragma unroll
  for (int mt = 0; mt < 4; ++mt) {
    const int m = m0 + mt * 16 + r;       // flat row = b*32 + a
    u16* orow = X1 + ((size_t)(m & 31) * 4096 + (size_t)(m >> 5)) * 512;
#pragma unroll
    for (int nt = 0; nt < 8; ++nt) {
      const int col = w * 128 + nt * 16 + q * 4;
      const float4 bb = *(const float4*)&bsh[col];
      const f32x4 v = acc[mt][nt];
      const u16x4 d = { f2bf(fmaxf(v.x + bb.x, 0.f)), f2bf(fmaxf(v.y + bb.y, 0.f)),
                        f2bf(fmaxf(v.z + bb.z, 0.f)), f2bf(fmaxf(v.w + bb.w, 0.f)) };
      *(u16x4*)&orow[col] = d;
    }
  }
}

// ---------------------------------------------------------------------------
// gemm23: per (64-row tile, agent):
//   L2: h = relu(x1[a] @ W1[a]^T + b1[a])   (acc in regs; A,B via gl_lds)
//   h -> LDS (padded rows, k-contiguous), then
//   L3: out = h @ W2[a]^T + b2[a]           (B-frags direct from global/L2)
// LDS max 65 KB -> 2 blocks/CU.
// ---------------------------------------------------------------------------
__global__ __launch_bounds__(256, 2)
void gemm23(const u16* __restrict__ X1, const u16* __restrict__ W1t,
            const float* __restrict__ b1, const u16* __restrict__ W2t,
            const float* __restrict__ b2, const int* __restrict__ route,
            float* __restrict__ Out) {
  __shared__ u16 lds[33280];              // 66560 B
  u16* As = lds;                          // [64 m][32 k]   (L2 loop)
  u16* Bs = lds + 2048;                   // [512 n][32 k]  (L2 loop)
  u16* Hs = lds;                          // [64 m][520]    (L3 phase, padded)

  const int tid = threadIdx.x;
  const int w = tid >> 6, l = tid & 63;
  const int r = l & 15, q = l >> 4;
  const int a = blockIdx.y;
  const int b0 = blockIdx.x * 64;
  const int rt = route[a];
  const u16* X1a = X1 + (size_t)a * 4096 * 512;
  const u16* W1a = W1t + (size_t)a * 262144;
  const u16* W2a = W2t + (size_t)a * 16384;

  // A staging: 1 gl_lds16 slot per thread (64 x 32 = 4 KB)
  const int arow = tid >> 2, as_ = tid & 3;
  const int asrc = (b0 + arow) * 512 + ((as_ ^ ((arow >> 1) & 3)) << 3);
  const int adst = tid * 8;
  // B staging: 8 slots per thread
  int bsrc[8], bdst[8];
#pragma unroll
  for (int c = 0; c < 8; ++c) {
    const int p = c * 256 + tid;
    const int n = p >> 2, s = p & 3;
    bsrc[c] = n * 512 + ((s ^ ((n >> 1) & 3)) << 3);
    bdst[c] = p * 8;
  }
  int aoff[4], boff[8];
#pragma unroll
  for (int t = 0; t < 4; ++t)
    aoff[t] = (t * 16 + r) * 32 + ((q ^ ((r >> 1) & 3)) << 3);
#pragma unroll
  for (int t = 0; t < 8; ++t)
    boff[t] = (w * 128 + t * 16 + r) * 32 + ((q ^ ((r >> 1) & 3)) << 3);

  f32x4 acc[4][8];
#pragma unroll
  for (int mt = 0; mt < 4; ++mt)
#pragma unroll
    for (int nt = 0; nt < 8; ++nt) acc[mt][nt] = (f32x4){0.f, 0.f, 0.f, 0.f};

  // ---------------- L2 K-loop ----------------
  for (int kt = 0; kt < 16; ++kt) {
    __syncthreads();
    gl_lds16(X1a + asrc + kt * 32, &As[adst]);
#pragma unroll
    for (int c = 0; c < 8; ++c) gl_lds16(W1a + bsrc[c] + kt * 32, &Bs[bdst[c]]);
    __syncthreads();
    bf16x8 af[4], bv[8];
#pragma unroll
    for (int t = 0; t < 4; ++t) af[t] = *(const bf16x8*)&As[aoff[t]];
#pragma unroll
    for (int t = 0; t < 8; ++t) bv[t] = *(const bf16x8*)&Bs[boff[t]];
#pragma unroll
    for (int mt = 0; mt < 4; ++mt)
#pragma unroll
      for (int nt = 0; nt < 8; ++nt)
        acc[mt][nt] = __builtin_amdgcn_mfma_f32_16x16x32_bf16(bv[nt], af[mt], acc[mt][nt], 0, 0, 0);
  }
  __syncthreads();                        // all L2 LDS reads done before Hs overwrite

  // relu+bias -> Hs [64][520] (pad 8 u16 -> conflict-free, no XOR swizzle)
#pragma unroll
  for (int mt = 0; mt < 4; ++mt) {
    const int m = mt * 16 + r;
#pragma unroll
    for (int nt = 0; nt < 8; ++nt) {
      const int col = w * 128 + nt * 16 + q * 4;
      const float4 bb = *(const float4*)&b1[(size_t)rt * 512 + col];
      const f32x4 v = acc[mt][nt];
      const u16x4 d = { f2bf(fmaxf(v.x + bb.x, 0.f)), f2bf(fmaxf(v.y + bb.y, 0.f)),
                        f2bf(fmaxf(v.z + bb.z, 0.f)), f2bf(fmaxf(v.w + bb.w, 0.f)) };
      *(u16x4*)&Hs[m * 520 + col] = d;
    }
  }
  __syncthreads();

  // ---------------- L3 ----------------
  // out tile 64x32: wave w -> m-frag mt=w; nt = 0..1.  B from global (L2-hot).
  {
    const int m = w * 16 + r;
    f32x4 o[2] = { (f32x4){0.f, 0.f, 0.f, 0.f}, (f32x4){0.f, 0.f, 0.f, 0.f} };
#pragma unroll 4
    for (int kt = 0; kt < 16; ++kt) {
      bf16x8 bf[2];
#pragma unroll
      for (int nt = 0; nt < 2; ++nt)
        bf[nt] = *(const bf16x8*)&W2a[(nt * 16 + r) * 512 + kt * 32 + q * 8];
      const bf16x8 af = *(const bf16x8*)&Hs[m * 520 + kt * 32 + q * 8];
#pragma unroll
      for (int nt = 0; nt < 2; ++nt)
        o[nt] = __builtin_amdgcn_mfma_f32_16x16x32_bf16(bf[nt], af, o[nt], 0, 0, 0);
    }
#pragma unroll
    for (int nt = 0; nt < 2; ++nt) {
      const int col = nt * 16 + q * 4;
      const float4 bb = *(const float4*)&b2[rt * 32 + col];
      const float4 res = { o[nt].x + bb.x, o[nt].y + bb.y, o[nt].z + bb.z, o[nt].w + bb.w };
      *(float4*)&Out[(size_t)(b0 + m) * 1024 + a * 32 + col] = res;
    }
  }
}

// ---------------------------------------------------------------------------
extern "C" void kernel_launch(void* const* d_in, const int* in_sizes, int n_in,
                              void* d_out, int out_size, void* d_ws, size_t ws_size,
                              hipStream_t stream) {
  (void)in_sizes; (void)n_in; (void)out_size; (void)ws_size;
  const float* x0  = (const float*)d_in[0];
  const float* Wsh = (const float*)d_in[1];
  const float* bsh = (const float*)d_in[2];
  const float* W1  = (const float*)d_in[3];
  const float* b1  = (const float*)d_in[4];
  const float* W2  = (const float*)d_in[5];
  const float* b2  = (const float*)d_in[6];
  const int* route = (const int*)d_in[7];
  float* out = (float*)d_out;

  char* ws = (char*)d_ws;
  u16* Wst = (u16*)(ws + 0);                      // 512*512*2    = 512 KB  [n][k]
  u16* W1t = (u16*)(ws + 524288);                 // 32*512*512*2 = 16 MB   [a][n][k]
  u16* W2t = (u16*)(ws + 524288 + 16777216);      // 32*32*512*2  = 1 MB    [a][n][k]
  u16* X1  = (u16*)(ws + 18350080);               // 32*4096*512*2 = 128 MB [a][b][h]

  transpose_cvt<<<dim3(16, 16, 1),  dim3(32, 8), 0, stream>>>(Wsh, nullptr, Wst, 512, 512);
  transpose_cvt<<<dim3(16, 16, 32), dim3(32, 8), 0, stream>>>(W1, route, W1t, 512, 512);
  transpose_cvt<<<dim3(16, 1, 32),  dim3(32, 8), 0, stream>>>(W2, route, W2t, 512, 32);
  gemm1<<<dim3(2048), 256, 0, stream>>>(x0, Wst, bsh, X1);
  gemm23<<<dim3(64, 32), 256, 0, stream>>>(X1, W1t, b1, W2t, b2, route, out);
}